// Round 2
// baseline (492.897 us; speedup 1.0000x reference)
//
#include <hip/hip_runtime.h>
#include <hip/hip_bf16.h>

using bf16 = __hip_bfloat16;
typedef __attribute__((ext_vector_type(8))) short short8;
typedef __attribute__((ext_vector_type(4))) float f32x4;

__device__ __forceinline__ float b2f(bf16 v){ return __bfloat162float(v); }
__device__ __forceinline__ float sigf(float v){ return 1.f/(1.f + __expf(-v)); }
__device__ __forceinline__ float ldv(const float* p, int i){ return p[i]; }
__device__ __forceinline__ float ldv(const bf16* p, int i){ return b2f(p[i]); }
__device__ __forceinline__ void stv(float* p, int i, float v){ p[i] = v; }
__device__ __forceinline__ void stv(bf16* p, int i, float v){ p[i] = __float2bfloat16(v); }

// ---------------------------------------------------------------------------
// K0: dtype detect. flag=1 => inputs are f32.
// ---------------------------------------------------------------------------
__global__ __launch_bounds__(256) void k_detect(const unsigned short* xs, int* flag){
  __shared__ int cnt;
  if (threadIdx.x == 0) cnt = 0;
  __syncthreads();
  int local = 0;
  for (int i = threadIdx.x; i < 16384; i += 256){
    if (((xs[i] >> 7) & 0xFF) == 0xFF) local++;
  }
  if (local) atomicAdd(&cnt, local);
  __syncthreads();
  if (threadIdx.x == 0) *flag = (cnt > 0) ? 1 : 0;
}

// ---------------------------------------------------------------------------
// K0b: canonicalize params. slots 0-17: fp32 in cpar; 18: w_def->bf16;
// 19: w_off->bf16 padded 18->32 rows; 20: w_g1->bf16; 21: w_cross->bf16;
// 22: w_out->bf16. grid (96, 23).
// ---------------------------------------------------------------------------
struct ParamSrc { const void* p[18]; };

__global__ __launch_bounds__(256) void k_convert(ParamSrc ps, const int* flagp,
    float* cpar, bf16* wdefb, bf16* woffb, bf16* wg1b, bf16* wcrossb, bf16* woutb){
  static constexpr int n[23]   = {41472,18,147456,131072,147456,64,64,64,64,64,
                                  16384,256,65536,256,256,256,256,256,
                                  147456,73728,147456,131072,65536};
  static constexpr int off[18] = {0,41472,41504,188960,320032,467488,467552,467616,
                                  467680,467744,467808,484192,484448,549984,550240,
                                  550496,550752,551008};
  const int s = blockIdx.y;
  const bool f32 = (*flagp != 0);
  if (s >= 18){
    static constexpr int srcs[5] = {2, 0, 4, 3, 12};
    const int src_slot = srcs[s - 18];
    bf16* dst = (s == 18) ? wdefb : (s == 19) ? woffb : (s == 20) ? wg1b
              : (s == 21) ? wcrossb : woutb;
    const int nsrc = (s == 19) ? 41472 : n[s];
    if (f32){
      const float* src = (const float*)ps.p[src_slot];
      for (int i = blockIdx.x * 256 + threadIdx.x; i < n[s]; i += gridDim.x * 256)
        dst[i] = (i < nsrc) ? __float2bfloat16(src[i]) : __float2bfloat16(0.f);
    } else {
      const bf16* src = (const bf16*)ps.p[src_slot];
      for (int i = blockIdx.x * 256 + threadIdx.x; i < n[s]; i += gridDim.x * 256)
        dst[i] = (i < nsrc) ? src[i] : __float2bfloat16(0.f);
    }
    return;
  }
  float* dst = cpar + off[s];
  if (f32){
    const float* src = (const float*)ps.p[s];
    for (int i = blockIdx.x * 256 + threadIdx.x; i < n[s]; i += gridDim.x * 256)
      dst[i] = src[i];
  } else {
    const bf16* src = (const bf16*)ps.p[s];
    for (int i = blockIdx.x * 256 + threadIdx.x; i < n[s]; i += gridDim.x * 256)
      dst[i] = b2f(src[i]);
  }
}

// ---------------------------------------------------------------------------
// Generic 3x3 pad=1 conv via im2col + MFMA. Block = one image row (64 px),
// 256 thr, grid 256 (b*64+y). K=2304 in 8 chunks of 288 (32 ch x 9 taps).
// LDS cols layout [k][pos] (pad 68): pixel-pair-packed b32 writes are
// conflict-free; B-frag u16 reads are 2-way (free). A-frags: bf16 weights
// from global (L2-resident). COT = #16-co m-tiles. EPI: BN+SiLU epilogue.
// ---------------------------------------------------------------------------
template<typename T, int COT, bool EPI>
__device__ __forceinline__ void conv3_body(const T* __restrict__ xin,
    const bf16* __restrict__ wb, const float* __restrict__ cbv,
    const float* __restrict__ gam, const float* __restrict__ bet,
    const float* __restrict__ mea, const float* __restrict__ var,
    float* __restrict__ outp, int co_lim, unsigned short* cols){
  const int bx = blockIdx.x;
  const int b = bx >> 6, y = bx & 63;
  const int t = threadIdx.x;
  const int l = t & 63, w = t >> 6;
  const int lm = l & 15, lq = l >> 4;
  const int pos2 = t & 31, kq = t >> 5;
  unsigned int* cols32 = (unsigned int*)cols;
  f32x4 acc[COT];
  #pragma unroll
  for (int m = 0; m < COT; m++) acc[m] = (f32x4){0.f,0.f,0.f,0.f};

  for (int cc = 0; cc < 256; cc += 32){
    __syncthreads();
    // ---- gather: 4 channels (kq*4..+4) x 9 taps x pixel pair (2*pos2, +1)
    #pragma unroll
    for (int c8 = 0; c8 < 4; c8++){
      const int c_local = kq * 4 + c8;
      const T* xc = xin + (b * 256 + cc + c_local) * 4096;
      #pragma unroll
      for (int tap = 0; tap < 9; tap++){
        const int ti = tap / 3, tj = tap % 3;
        const int yy = y + ti - 1;
        const int px0 = 2 * pos2 + tj - 1;
        const bool vy = (unsigned)yy < 64u;
        float v0 = (vy && (unsigned)px0 < 64u) ? ldv(xc, yy * 64 + px0) : 0.f;
        float v1 = (vy && (unsigned)(px0 + 1) < 64u) ? ldv(xc, yy * 64 + px0 + 1) : 0.f;
        bf16 h0 = __float2bfloat16(v0), h1 = __float2bfloat16(v1);
        unsigned int packed = (unsigned int)*(unsigned short*)&h0
                            | ((unsigned int)*(unsigned short*)&h1 << 16);
        cols32[(c_local * 9 + tap) * 34 + pos2] = packed;
      }
    }
    __syncthreads();
    // ---- MFMA: 9 ksteps of 32 over this chunk
    #pragma unroll
    for (int kk = 0; kk < 288; kk += 32){
      short8 bfr;
      #pragma unroll
      for (int j = 0; j < 8; j++)
        bfr[j] = (short)cols[(kk + lq * 8 + j) * 68 + w * 16 + lm];
      #pragma unroll
      for (int m = 0; m < COT; m++){
        const bf16* ap = wb + (m * 16 + lm) * 2304 + cc * 9 + kk + lq * 8;
        short8 afr = *(const short8*)ap;
        acc[m] = __builtin_amdgcn_mfma_f32_16x16x32_bf16(afr, bfr, acc[m], 0, 0, 0);
      }
    }
  }
  // ---- epilogue: D col=lane&15 (pixel), row=(lane>>4)*4+reg (co)
  const int p = y * 64 + w * 16 + lm;
  #pragma unroll
  for (int m = 0; m < COT; m++){
    #pragma unroll
    for (int r = 0; r < 4; r++){
      const int co = m * 16 + lq * 4 + r;
      if (co >= co_lim) continue;
      float v = acc[m][r] + cbv[co];
      if constexpr (EPI){
        float inv = gam[co] * rsqrtf(var[co] + 1e-5f);
        v = v * inv + (bet[co] - mea[co] * inv);
        v = v * sigf(v);
      }
      outp[(b * co_lim + co) * 4096 + p] = v;
    }
  }
}

__global__ __launch_bounds__(256) void k_coff_m(const void* x, const int* flagp,
    const bf16* woffb, const float* cb, float* offc){
  __shared__ __align__(16) unsigned short cols[288 * 68];
  if (*flagp) conv3_body<float, 2, false>((const float*)x, woffb, cb,
                  nullptr, nullptr, nullptr, nullptr, offc, 18, cols);
  else        conv3_body<bf16, 2, false>((const bf16*)x, woffb, cb,
                  nullptr, nullptr, nullptr, nullptr, offc, 18, cols);
}

__global__ __launch_bounds__(256) void k_g1_m(const float* xdense,
    const bf16* wg1b, const float* cb, const float* gam, const float* bet,
    const float* mea, const float* var, float* abuf){
  __shared__ __align__(16) unsigned short cols[288 * 68];
  conv3_body<float, 4, true>(xdense, wg1b, cb, gam, bet, mea, var, abuf, 64, cols);
}

// ---------------------------------------------------------------------------
// K2: deformable conv, MFMA (unchanged — passed).
// ---------------------------------------------------------------------------
#define CROW 584

template<typename T>
__device__ __forceinline__ void deform_body(const T* __restrict__ x,
    const float* __restrict__ offc, const bf16* __restrict__ wdefb,
    float* __restrict__ xdir, unsigned short* cols){
  const int g = blockIdx.y;
  const int q0 = blockIdx.x * 32;
  const int b = q0 >> 12, p0 = q0 & 4095;
  const int t = threadIdx.x;
  {
    const int pos = t & 31, cb8 = t >> 5;
    const int p = p0 + pos;
    const int y = p >> 6, xx = p & 63;
    const float* ob = offc + b * 18 * 4096 + p;
    const T* xg = x + ((b * 4 + g) * 64) * 4096;
    #pragma unroll
    for (int k = 0; k < 9; k++){
      float dy = ob[(2 * k) * 4096];
      float dx = ob[(2 * k + 1) * 4096];
      float py = (float)(y + k / 3 - 1) + dy;
      float px = (float)(xx + k % 3 - 1) + dx;
      float y0f = floorf(py), x0f = floorf(px);
      int y0 = (int)y0f, x0 = (int)x0f;
      float wy1 = py - y0f, wx1 = px - x0f;
      float wy0 = 1.f - wy1, wx0 = 1.f - wx1;
      bool vy0 = (unsigned)y0 < 64u, vy1 = (unsigned)(y0 + 1) < 64u;
      bool vx0 = (unsigned)x0 < 64u, vx1 = (unsigned)(x0 + 1) < 64u;
      float w00 = (vy0 && vx0) ? wy0 * wx0 : 0.f;
      float w01 = (vy0 && vx1) ? wy0 * wx1 : 0.f;
      float w10 = (vy1 && vx0) ? wy1 * wx0 : 0.f;
      float w11 = (vy1 && vx1) ? wy1 * wx1 : 0.f;
      int yc0 = min(max(y0, 0), 63), yc1 = min(max(y0 + 1, 0), 63);
      int xc0 = min(max(x0, 0), 63), xc1 = min(max(x0 + 1, 0), 63);
      int i00 = yc0 * 64 + xc0, i01 = yc0 * 64 + xc1;
      int i10 = yc1 * 64 + xc0, i11 = yc1 * 64 + xc1;
      #pragma unroll
      for (int u = 0; u < 8; u++){
        int cl = cb8 * 8 + u;
        const T* xc = xg + cl * 4096;
        float val = w00 * ldv(xc, i00) + w01 * ldv(xc, i01)
                  + w10 * ldv(xc, i10) + w11 * ldv(xc, i11);
        bf16 hv = __float2bfloat16(val);
        cols[pos * CROW + cl * 9 + k] = *(unsigned short*)&hv;
      }
    }
  }
  __syncthreads();
  {
    const int w = t >> 6;
    const int l = t & 63;
    const int lrow = l & 15;
    const int lhi = l >> 4;
    f32x4 acc0 = {0.f, 0.f, 0.f, 0.f};
    f32x4 acc1 = {0.f, 0.f, 0.f, 0.f};
    const bf16* wr = wdefb + (g * 64 + w * 16 + lrow) * 576;
    const unsigned short* b0p = cols + lrow * CROW;
    const unsigned short* b1p = cols + (16 + lrow) * CROW;
    #pragma unroll 2
    for (int kk = 0; kk < 576; kk += 32){
      int ko = kk + lhi * 8;
      short8 a  = *(const short8*)(wr + ko);
      short8 b0 = *(const short8*)(b0p + ko);
      short8 b1 = *(const short8*)(b1p + ko);
      acc0 = __builtin_amdgcn_mfma_f32_16x16x32_bf16(a, b0, acc0, 0, 0, 0);
      acc1 = __builtin_amdgcn_mfma_f32_16x16x32_bf16(a, b1, acc1, 0, 0, 0);
    }
    const int co_base = g * 64 + w * 16 + lhi * 4;
    #pragma unroll
    for (int r = 0; r < 4; r++){
      float* xo = xdir + (b * 256 + co_base + r) * 4096 + p0 + lrow;
      xo[0]  = acc0[r];
      xo[16] = acc1[r];
    }
  }
}

__global__ __launch_bounds__(256) void k_deform(const void* x, const int* flagp,
    const float* offc, const bf16* wdefb, float* xdir){
  __shared__ __align__(16) unsigned short cols[32 * CROW];
  if (*flagp) deform_body((const float*)x, offc, wdefb, xdir, cols);
  else        deform_body((const bf16*)x, offc, wdefb, xdir, cols);
}

// ---------------------------------------------------------------------------
// K3: 1x1 conv concat([x_dir, x_prev]) * w_cross (256x512) — MFMA.
// Block = one (b,y) row (64 px), 256 thr, grid (256, 2); blockIdx.y picks
// a 128-co half (COT=8). K=512 staged in 8 chunks of 64 ch. Same LDS layout
// as conv3 ([k][pos], pad 68, pixel-pair b32 writes).
// ---------------------------------------------------------------------------
template<typename T>
__device__ __forceinline__ void cross_mfma_body(const float* __restrict__ xdir,
    const T* __restrict__ xprev, const bf16* __restrict__ wb,
    float* __restrict__ xdense, unsigned short* cols){
  const int bx = blockIdx.x;
  const int b = bx >> 6, y = bx & 63;
  const int co0 = blockIdx.y * 128;
  const int t = threadIdx.x;
  const int l = t & 63, w = t >> 6;
  const int lm = l & 15, lq = l >> 4;
  const int pos2 = t & 31, cq = t >> 5;
  unsigned int* cols32 = (unsigned int*)cols;
  f32x4 acc[8];
  #pragma unroll
  for (int m = 0; m < 8; m++) acc[m] = (f32x4){0.f,0.f,0.f,0.f};

  for (int cc = 0; cc < 512; cc += 64){
    __syncthreads();
    #pragma unroll
    for (int c8 = 0; c8 < 8; c8++){
      const int cl = cq * 8 + c8;
      const int ci = cc + cl;
      float v0, v1;
      if (ci < 256){
        const float* row = xdir + (b * 256 + ci) * 4096 + y * 64 + 2 * pos2;
        v0 = row[0]; v1 = row[1];
      } else {
        const T* row = xprev + (b * 256 + (ci - 256)) * 4096 + y * 64 + 2 * pos2;
        v0 = ldv(row, 0); v1 = ldv(row, 1);
      }
      bf16 h0 = __float2bfloat16(v0), h1 = __float2bfloat16(v1);
      unsigned int packed = (unsigned int)*(unsigned short*)&h0
                          | ((unsigned int)*(unsigned short*)&h1 << 16);
      cols32[cl * 34 + pos2] = packed;
    }
    __syncthreads();
    #pragma unroll
    for (int kk = 0; kk < 64; kk += 32){
      short8 bfr;
      #pragma unroll
      for (int j = 0; j < 8; j++)
        bfr[j] = (short)cols[(kk + lq * 8 + j) * 68 + w * 16 + lm];
      #pragma unroll
      for (int m = 0; m < 8; m++){
        const bf16* ap = wb + (co0 + m * 16 + lm) * 512 + cc + kk + lq * 8;
        short8 afr = *(const short8*)ap;
        acc[m] = __builtin_amdgcn_mfma_f32_16x16x32_bf16(afr, bfr, acc[m], 0, 0, 0);
      }
    }
  }
  const int p = y * 64 + w * 16 + lm;
  #pragma unroll
  for (int m = 0; m < 8; m++){
    #pragma unroll
    for (int r = 0; r < 4; r++){
      const int co = co0 + m * 16 + lq * 4 + r;
      xdense[(b * 256 + co) * 4096 + p] = acc[m][r];
    }
  }
}

__global__ __launch_bounds__(256) void k_cross(const float* xdir, const void* xprev,
    const int* flagp, const bf16* wcb, float* xdense){
  __shared__ __align__(16) unsigned short cols[64 * 68];
  if (*flagp) cross_mfma_body(xdir, (const float*)xprev, wcb, xdense, cols);
  else        cross_mfma_body(xdir, (const bf16*)xprev, wcb, xdense, cols);
}

// ---------------------------------------------------------------------------
// K5: 1x1 conv 64->256 + bias + sigmoid, xa = xdense * attn. grid (64,64).
// ---------------------------------------------------------------------------
__global__ __launch_bounds__(256) void k_attn(
    const float* __restrict__ abuf, const float* __restrict__ cw,
    const float* __restrict__ cb, const float* __restrict__ xdense,
    float* __restrict__ xa){
  const int q0 = blockIdx.x * 256;
  const int b = q0 >> 12, p0 = q0 & 4095;
  const int co0 = blockIdx.y * 4;
  const int p = p0 + threadIdx.x;
  float acc[4] = {0,0,0,0};
  const float* ab = abuf + b * 64 * 4096;
  for (int c = 0; c < 64; c++){
    float av = ab[c * 4096 + p];
    acc[0] += cw[(co0 + 0) * 64 + c] * av;
    acc[1] += cw[(co0 + 1) * 64 + c] * av;
    acc[2] += cw[(co0 + 2) * 64 + c] * av;
    acc[3] += cw[(co0 + 3) * 64 + c] * av;
  }
  #pragma unroll
  for (int j = 0; j < 4; j++){
    int co = co0 + j;
    float attn = sigf(acc[j] + cb[co]);
    int idx = (b * 256 + co) * 4096 + p;
    xa[idx] = xdense[idx] * attn;
  }
}

// ---------------------------------------------------------------------------
// K6: 1x1 conv 256->256 + bias + BN + SiLU + residual — MFMA.
// Same skeleton as k_cross: grid (256, 2), COT=8, K=256 in 4 chunks of 64.
// ---------------------------------------------------------------------------
template<typename T>
__device__ __forceinline__ void out_mfma_body(const float* __restrict__ xa,
    const bf16* __restrict__ wb, const float* __restrict__ cbv,
    const float* __restrict__ gam, const float* __restrict__ bet,
    const float* __restrict__ mea, const float* __restrict__ var,
    const T* __restrict__ xres, T* __restrict__ outp, unsigned short* cols){
  const int bx = blockIdx.x;
  const int b = bx >> 6, y = bx & 63;
  const int co0 = blockIdx.y * 128;
  const int t = threadIdx.x;
  const int l = t & 63, w = t >> 6;
  const int lm = l & 15, lq = l >> 4;
  const int pos2 = t & 31, cq = t >> 5;
  unsigned int* cols32 = (unsigned int*)cols;
  f32x4 acc[8];
  #pragma unroll
  for (int m = 0; m < 8; m++) acc[m] = (f32x4){0.f,0.f,0.f,0.f};

  for (int cc = 0; cc < 256; cc += 64){
    __syncthreads();
    #pragma unroll
    for (int c8 = 0; c8 < 8; c8++){
      const int cl = cq * 8 + c8;
      const int ci = cc + cl;
      const float* row = xa + (b * 256 + ci) * 4096 + y * 64 + 2 * pos2;
      float v0 = row[0], v1 = row[1];
      bf16 h0 = __float2bfloat16(v0), h1 = __float2bfloat16(v1);
      unsigned int packed = (unsigned int)*(unsigned short*)&h0
                          | ((unsigned int)*(unsigned short*)&h1 << 16);
      cols32[cl * 34 + pos2] = packed;
    }
    __syncthreads();
    #pragma unroll
    for (int kk = 0; kk < 64; kk += 32){
      short8 bfr;
      #pragma unroll
      for (int j = 0; j < 8; j++)
        bfr[j] = (short)cols[(kk + lq * 8 + j) * 68 + w * 16 + lm];
      #pragma unroll
      for (int m = 0; m < 8; m++){
        const bf16* ap = wb + (co0 + m * 16 + lm) * 256 + cc + kk + lq * 8;
        short8 afr = *(const short8*)ap;
        acc[m] = __builtin_amdgcn_mfma_f32_16x16x32_bf16(afr, bfr, acc[m], 0, 0, 0);
      }
    }
  }
  const int p = y * 64 + w * 16 + lm;
  #pragma unroll
  for (int m = 0; m < 8; m++){
    #pragma unroll
    for (int r = 0; r < 4; r++){
      const int co = co0 + m * 16 + lq * 4 + r;
      float inv = gam[co] * rsqrtf(var[co] + 1e-5f);
      float v = acc[m][r] + cbv[co];
      v = v * inv + (bet[co] - mea[co] * inv);
      v = v * sigf(v);
      const int idx = (b * 256 + co) * 4096 + p;
      stv(outp, idx, v + ldv(xres, idx));
    }
  }
}

__global__ __launch_bounds__(256) void k_out(const float* xa, const bf16* wob,
    const float* cb, const float* gam, const float* bet, const float* mea,
    const float* var, const void* xres, void* out, const int* flagp){
  __shared__ __align__(16) unsigned short cols[64 * 68];
  if (*flagp) out_mfma_body(xa, wob, cb, gam, bet, mea, var,
                            (const float*)xres, (float*)out, cols);
  else        out_mfma_body(xa, wob, cb, gam, bet, mea, var,
                            (const bf16*)xres, (bf16*)out, cols);
}

// ---------------------------------------------------------------------------
extern "C" void kernel_launch(void* const* d_in, const int* in_sizes, int n_in,
                              void* d_out, int out_size, void* d_ws, size_t ws_size,
                              hipStream_t stream) {
  const void* x      = d_in[0];
  const void* x_prev = d_in[1];

  float* ws   = (float*)d_ws;
  int*   flag = (int*)ws;                 // ws[0..15] reserved
  float* cpar = ws + 16;                  // canonical fp32 params (551264 f)
  float* cb_off   = cpar + 41472;
  float* cb_g1    = cpar + 467488;
  float* cg1_gam  = cpar + 467552;
  float* cg1_bet  = cpar + 467616;
  float* cg1_mea  = cpar + 467680;
  float* cg1_var  = cpar + 467744;
  float* cw_g2    = cpar + 467808;
  float* cb_g2    = cpar + 484192;
  float* cb_out   = cpar + 549984;
  float* co_gam   = cpar + 550240;
  float* co_bet   = cpar + 550496;
  float* co_mea   = cpar + 550752;
  float* co_var   = cpar + 551008;

  bf16*  wdefb   = (bf16*)(ws + 551280);            // 147456 hw = 73728 f
  bf16*  woffb   = (bf16*)(ws + 625008);            // 73728 hw  = 36864 f
  bf16*  wg1b    = (bf16*)(ws + 661872);            // 147456 hw = 73728 f
  bf16*  wcrossb = (bf16*)(ws + 735600);            // 131072 hw = 65536 f
  bf16*  woutb   = (bf16*)(ws + 801136);            //  65536 hw = 32768 f
  float* base    = ws + 833904;
  float* offc   = base;                   // 4*18*4096  = 294912 f
  float* xdir   = offc + 294912;          // 4*256*4096 = 4194304 f
  float* xdense = xdir + 4194304;         // 4194304 f
  float* abuf   = xdense + 4194304;       // 1048576 f
  float* xa     = xdir;                   // reuse (xdir dead after K3)

  ParamSrc ps;
  for (int i = 0; i < 18; i++) ps.p[i] = d_in[2 + i];

  k_detect<<<dim3(1), 256, 0, stream>>>((const unsigned short*)x, flag);
  k_convert<<<dim3(96, 23), 256, 0, stream>>>(ps, flag, cpar, wdefb, woffb,
                                              wg1b, wcrossb, woutb);
  k_coff_m<<<dim3(256), 256, 0, stream>>>(x, flag, woffb, cb_off, offc);
  k_deform<<<dim3(512, 4), 256, 0, stream>>>(x, flag, offc, wdefb, xdir);
  k_cross<<<dim3(256, 2), 256, 0, stream>>>(xdir, x_prev, flag, wcrossb, xdense);
  k_g1_m<<<dim3(256), 256, 0, stream>>>(xdense, wg1b, cb_g1, cg1_gam, cg1_bet,
                                        cg1_mea, cg1_var, abuf);
  k_attn<<<dim3(64, 64), 256, 0, stream>>>(abuf, cw_g2, cb_g2, xdense, xa);
  k_out<<<dim3(256, 2), 256, 0, stream>>>(xa, woutb, cb_out, co_gam, co_bet,
                                          co_mea, co_var, x, d_out, flag);
}